// Round 9
// baseline (668.988 us; speedup 1.0000x reference)
//
#include <hip/hip_runtime.h>
#include <math.h>

// ---------------------------------------------------------------------------
// JPEG-domain ViT. Round 9: mm_k grids were co-residency-limited (1.5-3
// blocks/CU x 4 waves = 6-12 waves/CU). mm_k now runs 8 waves/block with a
// kc-split: waves 0-3 compute the low 32 K-columns of each BK=64 step,
// waves 4-7 the high 32 (same staged tile, same LDS traffic, 2x TLP),
// followed by one 32KB LDS reduction. Staging/swizzle identical to round 8
// (full-cache-line gload16, involution chunk swizzle, counted vmcnt).
// ---------------------------------------------------------------------------

#define NIMG 16
#define SEQ 192
#define DIMV 1024
#define MROWS (NIMG * SEQ)   // 3072

typedef __attribute__((ext_vector_type(8))) short short8v;
typedef __attribute__((ext_vector_type(4))) float f32x4;
typedef unsigned int uint_t;

__device__ __forceinline__ unsigned short f2bf(float f) {
  union { float f; uint_t u; } x; x.f = f;
  uint_t r = x.u + 0x7fffu + ((x.u >> 16) & 1u);
  return (unsigned short)(r >> 16);
}

__device__ __forceinline__ void gload16(const void* g, void* l) {
  __builtin_amdgcn_global_load_lds(
      reinterpret_cast<const __attribute__((address_space(1))) void*>(
          reinterpret_cast<uintptr_t>(g)),
      reinterpret_cast<__attribute__((address_space(3))) void*>(
          reinterpret_cast<uintptr_t>(l)),
      16, 0, 0);
}

__constant__ float DCT8c[8][8] = {
  { 0.35355339f, 0.35355339f, 0.35355339f, 0.35355339f, 0.35355339f, 0.35355339f, 0.35355339f, 0.35355339f},
  { 0.49039264f, 0.41573481f, 0.27778512f, 0.09754516f,-0.09754516f,-0.27778512f,-0.41573481f,-0.49039264f},
  { 0.46193977f, 0.19134172f,-0.19134172f,-0.46193977f,-0.46193977f,-0.19134172f, 0.19134172f, 0.46193977f},
  { 0.41573481f,-0.09754516f,-0.49039264f,-0.27778512f, 0.27778512f, 0.49039264f, 0.09754516f,-0.41573481f},
  { 0.35355339f,-0.35355339f,-0.35355339f, 0.35355339f, 0.35355339f,-0.35355339f,-0.35355339f, 0.35355339f},
  { 0.27778512f,-0.49039264f, 0.09754516f, 0.41573481f,-0.41573481f,-0.09754516f, 0.49039264f,-0.27778512f},
  { 0.19134172f,-0.46193977f, 0.46193977f,-0.19134172f,-0.19134172f, 0.46193977f,-0.46193977f, 0.19134172f},
  { 0.09754516f,-0.27778512f, 0.41573481f,-0.49039264f, 0.49039264f,-0.41573481f, 0.27778512f,-0.09754516f}
};

// ---------------- preprocess (coalesced): block = (hb, n) ------------------
__global__ __launch_bounds__(256) void preproc_k(const float* __restrict__ img,
                                                 float* __restrict__ x0) {
  int hb = blockIdx.x, n = blockIdx.y;
  __shared__ float yuv[3][8][256];
  __shared__ float tmpA[8][264];
  __shared__ float coefc[64][33];
  int t = threadIdx.x;

  #pragma unroll
  for (int u = 0; u < 8; ++u) {
    int idx = u * 256 + t;
    int i = idx >> 8, xx = idx & 255;
    size_t pix = ((size_t)(n * 3) * 256 + hb * 8 + i) * 256 + xx;
    float r = img[pix], g = img[pix + 65536], b = img[pix + 131072];
    yuv[0][i][xx] =  0.299f   * r + 0.587f   * g + 0.114f   * b;
    yuv[1][i][xx] = -0.14713f * r - 0.28886f * g + 0.436f   * b;
    yuv[2][i][xx] =  0.615f   * r - 0.51499f * g - 0.10001f * b;
  }

  for (int c = 0; c < 3; ++c) {
    __syncthreads();
    #pragma unroll
    for (int u = 0; u < 8; ++u) {
      int idx = u * 256 + t;
      int p = idx >> 8, xx = idx & 255;
      float a = 0.f;
      #pragma unroll
      for (int k = 0; k < 8; ++k) a += DCT8c[p][k] * yuv[c][k][xx];
      tmpA[p][xx] = a;
    }
    __syncthreads();
    #pragma unroll
    for (int u = 0; u < 8; ++u) {
      int idx = u * 256 + t;
      int wb = idx >> 6, s = idx & 63;
      int p = s >> 3, qq = s & 7;
      float a = 0.f;
      #pragma unroll
      for (int j = 0; j < 8; ++j) a += tmpA[p][wb * 8 + j] * DCT8c[qq][j];
      bool keep = (c == 0) ? ((p + qq) <= 5 || ((p + qq) == 6 && qq < 4))
                           : ((p + qq) <= 2 || ((p + qq) == 3 && p < 3));
      coefc[s][wb] = keep ? a : 0.f;
    }
    __syncthreads();
    #pragma unroll
    for (int u = 0; u < 8; ++u) {
      int idx = u * 256 + t;
      int s = idx >> 5, wb = idx & 31;
      x0[((size_t)(n * SEQ) + c * 64 + s) * DIMV + hb * 32 + wb] = coefc[s][wb];
    }
  }
}

// ---------------- postprocess (coalesced): block = (hb, n) ------------------
__global__ __launch_bounds__(256) void postproc_k(const float* __restrict__ x,
                                                  float* __restrict__ out) {
  int hb = blockIdx.x, n = blockIdx.y;
  __shared__ float coefc[64][33];
  __shared__ float tmpA[8][264];
  __shared__ float rec[3][8][256];
  int t = threadIdx.x;

  for (int c = 0; c < 3; ++c) {
    __syncthreads();
    #pragma unroll
    for (int u = 0; u < 8; ++u) {
      int idx = u * 256 + t;
      int s = idx >> 5, wb = idx & 31;
      coefc[s][wb] = x[((size_t)(n * SEQ) + c * 64 + s) * DIMV + hb * 32 + wb];
    }
    __syncthreads();
    #pragma unroll
    for (int u = 0; u < 8; ++u) {
      int idx = u * 256 + t;
      int wb = idx >> 6, iq = idx & 63;
      int i = iq >> 3, qq = iq & 7;
      float a = 0.f;
      #pragma unroll
      for (int p = 0; p < 8; ++p) a += DCT8c[i][p] * coefc[p * 8 + qq][wb];
      tmpA[i][wb * 8 + qq] = a;
    }
    __syncthreads();
    #pragma unroll
    for (int u = 0; u < 8; ++u) {
      int idx = u * 256 + t;
      int i = idx >> 8, xx = idx & 255;
      int wb = xx >> 3, j = xx & 7;
      float a = 0.f;
      #pragma unroll
      for (int qq = 0; qq < 8; ++qq) a += tmpA[i][wb * 8 + qq] * DCT8c[j][qq];
      rec[c][i][xx] = a;
    }
  }
  __syncthreads();
  #pragma unroll
  for (int u = 0; u < 8; ++u) {
    int idx = u * 256 + t;
    int i = idx >> 8, xx = idx & 255;
    float y = rec[0][i][xx], uu = rec[1][i][xx], v = rec[2][i][xx];
    size_t pix = ((size_t)(n * 3) * 256 + hb * 8 + i) * 256 + xx;
    out[pix]          = y + 1.13983f * v;
    out[pix + 65536]  = y - 0.39465f * uu - 0.5806f * v;
    out[pix + 131072] = y + 2.03211f * uu;
  }
}

// ---------------- weight transpose+convert: w[K][N] fp32 -> wt[N][K] bf16 ---
__global__ __launch_bounds__(256) void wconv_k(const float* __restrict__ w,
                                               unsigned short* __restrict__ wt,
                                               int K, int N) {
  size_t off = (size_t)blockIdx.z * K * N;
  w += off; wt += off;
  __shared__ float s[32][33];
  int t = threadIdx.x;
  int n0 = blockIdx.x << 5, k0 = blockIdx.y << 5;
  int r = t >> 3, c4 = (t & 7) << 2;
  float4 v = *(const float4*)(w + (size_t)(k0 + r) * N + n0 + c4);
  s[r][c4] = v.x; s[r][c4 + 1] = v.y; s[r][c4 + 2] = v.z; s[r][c4 + 3] = v.w;
  __syncthreads();
  ushort4 o;
  o.x = f2bf(s[c4 + 0][r]); o.y = f2bf(s[c4 + 1][r]);
  o.z = f2bf(s[c4 + 2][r]); o.w = f2bf(s[c4 + 3][r]);
  *(ushort4*)(wt + (size_t)(n0 + r) * K + k0 + c4) = o;
}

// ---------------- layernorm over last dim (1024): fp32 in -> bf16 out -------
__global__ __launch_bounds__(256) void ln_k(const float* __restrict__ x,
                                            const float* __restrict__ g,
                                            const float* __restrict__ b,
                                            unsigned short* __restrict__ out) {
  int row = blockIdx.x, t = threadIdx.x;
  float4 v = ((const float4*)(x + (size_t)row * DIMV))[t];
  float s  = v.x + v.y + v.z + v.w;
  float s2 = v.x * v.x + v.y * v.y + v.z * v.z + v.w * v.w;
  #pragma unroll
  for (int off = 32; off > 0; off >>= 1) {
    s  += __shfl_down(s,  off, 64);
    s2 += __shfl_down(s2, off, 64);
  }
  __shared__ float red[8];
  int w = t >> 6;
  if ((t & 63) == 0) { red[w] = s; red[4 + w] = s2; }
  __syncthreads();
  s  = red[0] + red[1] + red[2] + red[3];
  s2 = red[4] + red[5] + red[6] + red[7];
  float mu  = s * (1.f / 1024.f);
  float var = fmaxf(s2 * (1.f / 1024.f) - mu * mu, 0.f);
  float rs  = rsqrtf(var + 1e-5f);
  float4 gv = ((const float4*)g)[t];
  float4 bv = ((const float4*)b)[t];
  ushort4 ov;
  ov.x = f2bf((v.x - mu) * rs * gv.x + bv.x);
  ov.y = f2bf((v.y - mu) * rs * gv.y + bv.y);
  ov.z = f2bf((v.z - mu) * rs * gv.z + bv.z);
  ov.w = f2bf((v.w - mu) * rs * gv.w + bv.w);
  ((ushort4*)(out + (size_t)row * DIMV))[t] = ov;
}

// ---------------- bf16 MFMA GEMM: 128x64 tile, 8 waves, BK=64, kc-split -----
// C[M,N] = A[M,K] @ Bt[N,K]^T. Wave w: quadrant q=w&3 (wm=(q>>1)*64,
// wn=(q&1)*32), K-column half kc=w>>2 of each BK=64 step. Per step per wave:
// 6 ds_read_b128 + 8 MFMA. Staging: 3 gload16/wave, each 8 rows x 128 B
// (full cache lines). Counted vmcnt(3) 2-deep pipeline. 8-chunk XOR swizzle
// (pre-swizzled global source, linear LDS dest, swizzled ds_read).
// End: waves 4-7 (kc=1) reduce into waves 0-3 via 32KB of dead staging LDS.
// LDS: A[db] = db*16KB (128 x 128B); B[db] = 32KB + db*8KB (64 x 128B).
// EPI: 0 = plain->bf16, 1 = +bias+fp32 residual->fp32, 2 = +bias+GELU->bf16
template <int EPI>
__global__ __launch_bounds__(512) void mm_k(const unsigned short* __restrict__ A,
                                            const unsigned short* __restrict__ Bt,
                                            const float* __restrict__ bias,
                                            const float* res,
                                            void* Cout,
                                            int M, int N, int K) {
  __shared__ __align__(16) unsigned short smem[24576];   // 48 KB

  int t = threadIdx.x;
  int lane = t & 63, w = t >> 6;          // 8 waves
  int kc = w >> 2;                        // K-column half this wave computes
  int q  = w & 3;
  // bijective XCD swizzle (all grids here are divisible by 8)
  int gx = gridDim.x;
  int nwg = gx * gridDim.y;
  int bid = blockIdx.y * gx + blockIdx.x;
  bid = (bid & 7) * (nwg >> 3) + (bid >> 3);
  int m0 = (bid / gx) << 7, n0 = (bid % gx) << 6;
  int wm = (q >> 1) << 6, wn = (q & 1) << 5;

  // staging: wave w covers A rows [w*16, w*16+16) via 2 gloads, B rows
  // [w*8, w*8+8) via 1 gload. lane: row offset r_in = lane>>3, physical
  // chunk p = lane&7 -> loads logical chunk p^r_in of its row.
  int r_in = lane >> 3, p = lane & 7;
  int sw = (p ^ r_in) << 3;
  const unsigned short* Ag = A + (size_t)(m0 + w * 16 + r_in) * K + sw;
  const unsigned short* Bg = Bt + (size_t)(n0 + w * 8 + r_in) * K + sw;
  char* smb = (char*)smem;
  size_t K8 = (size_t)K * 8;

  f32x4 acc[4][2] = {};

  int m15 = lane & 15, c4 = lane >> 4, s7 = lane & 7;
  int ch = (kc << 2) + c4;                // logical 16B chunk 0..7
  int nt = K >> 6;

  #define STAGE(it_, db_) {                                                       \
    size_t k0_ = (size_t)(it_) << 6;                                              \
    gload16(Ag + k0_,      smb + (db_) * 16384 + ((w * 16 + 0) << 7));            \
    gload16(Ag + k0_ + K8, smb + (db_) * 16384 + ((w * 16 + 8) << 7));            \
    gload16(Bg + k0_,      smb + 32768 + (db_) * 8192 + ((w * 8) << 7)); }

  STAGE(0, 0);
  STAGE(1, 1);

  for (int it = 0; it < nt; ++it) {
    int db = it & 1;
    if (it + 1 < nt) asm volatile("s_waitcnt vmcnt(3)" ::: "memory");
    else             asm volatile("s_waitcnt vmcnt(0)" ::: "memory");
    __builtin_amdgcn_s_barrier();
    const char* Ab = smb + db * 16384;
    const char* Bb = smb + 32768 + db * 8192;
    short8v a[4], b[2];
    #pragma unroll
    for (int mi = 0; mi < 4; ++mi)
      a[mi] = *(const short8v*)(Ab + ((wm + mi * 16 + m15) << 7) + ((ch ^ s7) << 4));
    #pragma unroll
    for (int ni = 0; ni < 2; ++ni)
      b[ni] = *(const short8v*)(Bb + ((wn + ni * 16 + m15) << 7) + ((ch ^ s7) << 4));
    #pragma unroll
    for (int mi = 0; mi < 4; ++mi)
      #pragma unroll
      for (int ni = 0; ni < 2; ++ni)
        acc[mi][ni] = __builtin_amdgcn_mfma_f32_16x16x32_bf16(a[mi], b[ni], acc[mi][ni], 0, 0, 0);
    __builtin_amdgcn_s_barrier();
    if (it + 2 < nt) STAGE(it + 2, db);
  }
  #undef STAGE

  // ---- reduce waves 4-7 (kc=1) into waves 0-3 (staging LDS is dead) -------
  // 8 f32x4/lane -> 4 waves x 8 KB = 32 KB, single pass.
  __syncthreads();
  if (w >= 4) {
    #pragma unroll
    for (int mi = 0; mi < 4; ++mi)
      #pragma unroll
      for (int ni = 0; ni < 2; ++ni)
        *(f32x4*)(smb + (((w - 4) * 8 + mi * 2 + ni) << 10) + (lane << 4)) =
            acc[mi][ni];
  }
  __syncthreads();
  if (w >= 4) return;
  #pragma unroll
  for (int mi = 0; mi < 4; ++mi)
    #pragma unroll
    for (int ni = 0; ni < 2; ++ni)
      acc[mi][ni] +=
          *(const f32x4*)(smb + ((w * 8 + mi * 2 + ni) << 10) + (lane << 4));

  // epilogue: C/D frag layout col = lane&15, row = (lane>>4)*4 + r  [m89/m91]
  int cn = lane & 15;
  int rbq = (lane >> 4) << 2;
  #pragma unroll
  for (int mi = 0; mi < 4; ++mi) {
    #pragma unroll
    for (int ni = 0; ni < 2; ++ni) {
      int col = n0 + wn + ni * 16 + cn;
      #pragma unroll
      for (int r = 0; r < 4; ++r) {
        int row = m0 + wm + mi * 16 + rbq + r;
        float v = acc[mi][ni][r];
        if (EPI >= 1) v += bias[col];
        if (EPI == 1) {
          ((float*)Cout)[(size_t)row * N + col] = v + res[(size_t)row * N + col];
        } else if (EPI == 2) {
          v = 0.5f * v * (1.f + erff(v * 0.70710678f));
          ((unsigned short*)Cout)[(size_t)row * N + col] = f2bf(v);
        } else {
          ((unsigned short*)Cout)[(size_t)row * N + col] = f2bf(v);
        }
      }
    }
  }
}

// ---------------- MFMA attention (round 3, unchanged) -----------------------
__global__ __launch_bounds__(256) void attn_k(const unsigned short* __restrict__ qkv,
                                              unsigned short* __restrict__ o) {
  int qt = blockIdx.x, h = blockIdx.y, n = blockIdx.z;
  int t = threadIdx.x, lane = t & 63, w = t >> 6;
  __shared__ __align__(16) unsigned short Ks[192 * 64];
  __shared__ __align__(16) unsigned short Vt[64 * 192];
  __shared__ __align__(16) unsigned short Ps[4][16 * 192];
  const unsigned short* base = qkv + (size_t)n * SEQ * 1536;

  #pragma unroll
  for (int i = 0; i < 6; ++i) {
    int idx = i * 256 + t;
    int row = idx >> 3, c8 = (idx & 7) << 3;
    short8v kv = *(const short8v*)(base + (size_t)row * 1536 + 512 + h * 64 + c8);
    int kb = (row * 128 + c8 * 2) ^ ((row & 7) << 4);
    *(short8v*)((char*)Ks + kb) = kv;
  }
  #pragma unroll
  for (int i = 0; i < 6; ++i) {
    int idx = i * 256 + t;
    int j = (idx & 63) + ((idx >> 9) << 6);
    int d0 = ((idx >> 6) & 7) << 3;
    short8v vv = *(const short8v*)(base + (size_t)j * 1536 + 1024 + h * 64 + d0);
    #pragma unroll
    for (int e = 0; e < 8; ++e) {
      int d = d0 + e;
      int vb = (d * 384 + j * 2) ^ ((d & 7) << 4);
      *(unsigned short*)((char*)Vt + vb) = (unsigned short)vv[e];
    }
  }
  int q0 = qt * 64 + w * 16;
  const unsigned short* qp = base + (size_t)(q0 + (lane & 15)) * 1536 + h * 64 + ((lane >> 4) << 3);
  short8v aq0 = *(const short8v*)(qp);
  short8v aq1 = *(const short8v*)(qp + 32);
  __syncthreads();

  f32x4 sa[12];
  #pragma unroll
  for (int ni = 0; ni < 12; ++ni) sa[ni] = (f32x4){0.f, 0.f, 0.f, 0.f};
  #pragma unroll
  for (int ks = 0; ks < 2; ++ks) {
    int kk = (ks << 5) + ((lane >> 4) << 3);
    short8v aq = ks ? aq1 : aq0;
    #pragma unroll
    for (int ni = 0; ni < 12; ++ni) {
      int krow = ni * 16 + (lane & 15);
      int kb = (krow * 128 + kk * 2) ^ ((krow & 7) << 4);
      short8v bk = *(const short8v*)((char*)Ks + kb);
      sa[ni] = __builtin_amdgcn_mfma_f32_16x16x32_bf16(aq, bk, sa[ni], 0, 0, 0);
    }
  }

  unsigned short* Pw = Ps[w];
  float l4[4];
  #pragma unroll
  for (int r = 0; r < 4; ++r) {
    float mx = sa[0][r];
    #pragma unroll
    for (int ni = 1; ni < 12; ++ni) mx = fmaxf(mx, sa[ni][r]);
    mx = fmaxf(mx, __shfl_xor(mx, 1, 64));
    mx = fmaxf(mx, __shfl_xor(mx, 2, 64));
    mx = fmaxf(mx, __shfl_xor(mx, 4, 64));
    mx = fmaxf(mx, __shfl_xor(mx, 8, 64));
    int prow = ((lane >> 4) << 2) + r;
    float sum = 0.f;
    #pragma unroll
    for (int ni = 0; ni < 12; ++ni) {
      float p = __expf((sa[ni][r] - mx) * 0.125f);
      sum += p;
      int col = ni * 16 + (lane & 15);
      int pb = (prow * 384 + col * 2) ^ ((prow & 7) << 4);
      *(unsigned short*)((char*)Pw + pb) = f2bf(p);
    }
    sum += __shfl_xor(sum, 1, 64);
    sum += __shfl_xor(sum, 2, 64);
    sum += __shfl_xor(sum, 4, 64);
    sum += __shfl_xor(sum, 8, 64);
    l4[r] = sum;
  }

  f32x4 oa[4];
  #pragma unroll
  for (int ni = 0; ni < 4; ++ni) oa[ni] = (f32x4){0.f, 0.f, 0.f, 0.f};
  #pragma unroll
  for (int ks = 0; ks < 6; ++ks) {
    int kk = (ks << 5) + ((lane >> 4) << 3);
    int m = lane & 15;
    int pb = (m * 384 + kk * 2) ^ ((m & 7) << 4);
    short8v pa = *(const short8v*)((char*)Pw + pb);
    #pragma unroll
    for (int ni = 0; ni < 4; ++ni) {
      int vrow = ni * 16 + (lane & 15);
      int vb = (vrow * 384 + kk * 2) ^ ((vrow & 7) << 4);
      short8v vbf = *(const short8v*)((char*)Vt + vb);
      oa[ni] = __builtin_amdgcn_mfma_f32_16x16x32_bf16(pa, vbf, oa[ni], 0, 0, 0);
    }
  }

  int rbq = (lane >> 4) << 2;
  #pragma unroll
  for (int r = 0; r < 4; ++r) {
    float inv = 1.f / l4[r];
    unsigned short* dst = o + (size_t)(n * SEQ + q0 + rbq + r) * 512 + h * 64 + (lane & 15);
    #pragma unroll
    for (int ni = 0; ni < 4; ++ni)
      dst[ni * 16] = f2bf(oa[ni][r] * inv);
  }
}

// ---------------------------------------------------------------------------
extern "C" void kernel_launch(void* const* d_in, const int* in_sizes, int n_in,
                              void* d_out, int out_size, void* d_ws, size_t ws_size,
                              hipStream_t stream) {
  const float* img   = (const float*)d_in[0];
  const float* ln1_g = (const float*)d_in[1];
  const float* ln1_b = (const float*)d_in[2];
  const float* wqkv  = (const float*)d_in[3];
  const float* wo    = (const float*)d_in[4];
  const float* bo    = (const float*)d_in[5];
  const float* ln2_g = (const float*)d_in[6];
  const float* ln2_b = (const float*)d_in[7];
  const float* w1    = (const float*)d_in[8];
  const float* b1    = (const float*)d_in[9];
  const float* w2    = (const float*)d_in[10];
  const float* b2    = (const float*)d_in[11];
  float* out = (float*)d_out;

  char* ws = (char*)d_ws;
  float*          x   = (float*)ws;                         // 12,582,912
  unsigned short* xn  = (unsigned short*)(ws + 12582912);   //  6,291,456
  unsigned short* big = (unsigned short*)(ws + 18874368);   // 12,582,912
  unsigned short* ob  = (unsigned short*)(ws + 31457280);   //  3,145,728
  unsigned short* wtb = (unsigned short*)(ws + 34603008);   // weight area

  bool big_ws = (ws_size >= 110100480ull);
  size_t per_qkv = (size_t)1024 * 1536, per_o = (size_t)512 * 1024;
  size_t per_1   = (size_t)1024 * 2048, per_2 = (size_t)2048 * 1024;
  unsigned short *wt_qkv, *wt_o, *wt_1, *wt_2;
  if (big_ws) {
    wt_qkv = wtb;
    wt_o   = wt_qkv + 6 * per_qkv;
    wt_1   = wt_o   + 6 * per_o;
    wt_2   = wt_1   + 6 * per_1;
    wconv_k<<<dim3(1536 / 32, 1024 / 32, 6), 256, 0, stream>>>(wqkv, wt_qkv, 1024, 1536);
    wconv_k<<<dim3(1024 / 32,  512 / 32, 6), 256, 0, stream>>>(wo,   wt_o,    512, 1024);
    wconv_k<<<dim3(2048 / 32, 1024 / 32, 6), 256, 0, stream>>>(w1,   wt_1,   1024, 2048);
    wconv_k<<<dim3(1024 / 32, 2048 / 32, 6), 256, 0, stream>>>(w2,   wt_2,   2048, 1024);
  } else {
    wt_qkv = wtb;
    wt_o   = wt_qkv + per_qkv;
    wt_1   = wt_o + per_o;
    wt_2   = wt_1 + per_1;
  }

  preproc_k<<<dim3(32, 16), 256, 0, stream>>>(img, x);

  for (int l = 0; l < 6; ++l) {
    unsigned short *wq_l, *wo_l, *w1_l, *w2_l;
    if (big_ws) {
      wq_l = wt_qkv + l * per_qkv; wo_l = wt_o + l * per_o;
      w1_l = wt_1 + l * per_1;     w2_l = wt_2 + l * per_2;
    } else {
      wconv_k<<<dim3(1536 / 32, 1024 / 32), 256, 0, stream>>>(wqkv + l * per_qkv, wt_qkv, 1024, 1536);
      wconv_k<<<dim3(1024 / 32,  512 / 32), 256, 0, stream>>>(wo   + l * per_o,   wt_o,    512, 1024);
      wconv_k<<<dim3(2048 / 32, 1024 / 32), 256, 0, stream>>>(w1   + l * per_1,   wt_1,   1024, 2048);
      wconv_k<<<dim3(1024 / 32, 2048 / 32), 256, 0, stream>>>(w2   + l * per_2,   wt_2,   2048, 1024);
      wq_l = wt_qkv; wo_l = wt_o; w1_l = wt_1; w2_l = wt_2;
    }

    ln_k<<<MROWS, 256, 0, stream>>>(x, ln1_g + l * 1024, ln1_b + l * 1024, xn);
    mm_k<0><<<dim3(1536 / 64, 24), 512, 0, stream>>>(xn, wq_l, nullptr, nullptr, big, MROWS, 1536, 1024);
    attn_k<<<dim3(3, 8, 16), 256, 0, stream>>>(big, ob);
    mm_k<1><<<dim3(1024 / 64, 24), 512, 0, stream>>>(ob, wo_l, bo + l * 1024, x, x, MROWS, 1024, 512);
    ln_k<<<MROWS, 256, 0, stream>>>(x, ln2_g + l * 1024, ln2_b + l * 1024, xn);
    mm_k<2><<<dim3(2048 / 64, 24), 512, 0, stream>>>(xn, w1_l, b1 + l * 2048, nullptr, big, MROWS, 2048, 1024);
    mm_k<1><<<dim3(1024 / 64, 24), 512, 0, stream>>>(big, w2_l, b2 + l * 1024, x, x, MROWS, 1024, 2048);
  }

  postproc_k<<<dim3(32, 16), 256, 0, stream>>>(x, out);
}

// Round 10
// 656.494 us; speedup vs baseline: 1.0190x; 1.0190x over previous
//
#include <hip/hip_runtime.h>
#include <math.h>

// ---------------------------------------------------------------------------
// JPEG-domain ViT. Round 10:
//  - mm_k reverted to the round-8 structure (4 waves, BK=64, full-cache-line
//    global_load_lds, counted vmcnt(6), involution chunk swizzle, XCD swizzle)
//    -- round-9's kc-split was neutral-negative (sync-bound, not TLP-bound).
//  - Residual stream x is now bf16 (fp32 accumulate, bf16 store): halves the
//    75 MB/layer of x traffic in wo/w2 epilogues + LN reads + pre/postproc.
// ---------------------------------------------------------------------------

#define NIMG 16
#define SEQ 192
#define DIMV 1024
#define MROWS (NIMG * SEQ)   // 3072

typedef __attribute__((ext_vector_type(8))) short short8v;
typedef __attribute__((ext_vector_type(4))) float f32x4;
typedef unsigned int uint_t;

__device__ __forceinline__ unsigned short f2bf(float f) {
  union { float f; uint_t u; } x; x.f = f;
  uint_t r = x.u + 0x7fffu + ((x.u >> 16) & 1u);
  return (unsigned short)(r >> 16);
}
__device__ __forceinline__ float bf2f(unsigned short h) {
  union { uint_t u; float f; } y; y.u = ((uint_t)h) << 16;
  return y.f;
}

__device__ __forceinline__ void gload16(const void* g, void* l) {
  __builtin_amdgcn_global_load_lds(
      reinterpret_cast<const __attribute__((address_space(1))) void*>(
          reinterpret_cast<uintptr_t>(g)),
      reinterpret_cast<__attribute__((address_space(3))) void*>(
          reinterpret_cast<uintptr_t>(l)),
      16, 0, 0);
}

__constant__ float DCT8c[8][8] = {
  { 0.35355339f, 0.35355339f, 0.35355339f, 0.35355339f, 0.35355339f, 0.35355339f, 0.35355339f, 0.35355339f},
  { 0.49039264f, 0.41573481f, 0.27778512f, 0.09754516f,-0.09754516f,-0.27778512f,-0.41573481f,-0.49039264f},
  { 0.46193977f, 0.19134172f,-0.19134172f,-0.46193977f,-0.46193977f,-0.19134172f, 0.19134172f, 0.46193977f},
  { 0.41573481f,-0.09754516f,-0.49039264f,-0.27778512f, 0.27778512f, 0.49039264f, 0.09754516f,-0.41573481f},
  { 0.35355339f,-0.35355339f,-0.35355339f, 0.35355339f, 0.35355339f,-0.35355339f,-0.35355339f, 0.35355339f},
  { 0.27778512f,-0.49039264f, 0.09754516f, 0.41573481f,-0.41573481f,-0.09754516f, 0.49039264f,-0.27778512f},
  { 0.19134172f,-0.46193977f, 0.46193977f,-0.19134172f,-0.19134172f, 0.46193977f,-0.46193977f, 0.19134172f},
  { 0.09754516f,-0.27778512f, 0.41573481f,-0.49039264f, 0.49039264f,-0.41573481f, 0.27778512f,-0.09754516f}
};

// ---------------- preprocess (coalesced): block = (hb, n), x bf16 ----------
__global__ __launch_bounds__(256) void preproc_k(const float* __restrict__ img,
                                                 unsigned short* __restrict__ x0) {
  int hb = blockIdx.x, n = blockIdx.y;
  __shared__ float yuv[3][8][256];
  __shared__ float tmpA[8][264];
  __shared__ float coefc[64][33];
  int t = threadIdx.x;

  #pragma unroll
  for (int u = 0; u < 8; ++u) {
    int idx = u * 256 + t;
    int i = idx >> 8, xx = idx & 255;
    size_t pix = ((size_t)(n * 3) * 256 + hb * 8 + i) * 256 + xx;
    float r = img[pix], g = img[pix + 65536], b = img[pix + 131072];
    yuv[0][i][xx] =  0.299f   * r + 0.587f   * g + 0.114f   * b;
    yuv[1][i][xx] = -0.14713f * r - 0.28886f * g + 0.436f   * b;
    yuv[2][i][xx] =  0.615f   * r - 0.51499f * g - 0.10001f * b;
  }

  for (int c = 0; c < 3; ++c) {
    __syncthreads();
    #pragma unroll
    for (int u = 0; u < 8; ++u) {
      int idx = u * 256 + t;
      int p = idx >> 8, xx = idx & 255;
      float a = 0.f;
      #pragma unroll
      for (int k = 0; k < 8; ++k) a += DCT8c[p][k] * yuv[c][k][xx];
      tmpA[p][xx] = a;
    }
    __syncthreads();
    #pragma unroll
    for (int u = 0; u < 8; ++u) {
      int idx = u * 256 + t;
      int wb = idx >> 6, s = idx & 63;
      int p = s >> 3, qq = s & 7;
      float a = 0.f;
      #pragma unroll
      for (int j = 0; j < 8; ++j) a += tmpA[p][wb * 8 + j] * DCT8c[qq][j];
      bool keep = (c == 0) ? ((p + qq) <= 5 || ((p + qq) == 6 && qq < 4))
                           : ((p + qq) <= 2 || ((p + qq) == 3 && p < 3));
      coefc[s][wb] = keep ? a : 0.f;
    }
    __syncthreads();
    #pragma unroll
    for (int u = 0; u < 8; ++u) {
      int idx = u * 256 + t;
      int s = idx >> 5, wb = idx & 31;
      x0[((size_t)(n * SEQ) + c * 64 + s) * DIMV + hb * 32 + wb] = f2bf(coefc[s][wb]);
    }
  }
}

// ---------------- postprocess (coalesced): block = (hb, n), x bf16 ---------
__global__ __launch_bounds__(256) void postproc_k(const unsigned short* __restrict__ x,
                                                  float* __restrict__ out) {
  int hb = blockIdx.x, n = blockIdx.y;
  __shared__ float coefc[64][33];
  __shared__ float tmpA[8][264];
  __shared__ float rec[3][8][256];
  int t = threadIdx.x;

  for (int c = 0; c < 3; ++c) {
    __syncthreads();
    #pragma unroll
    for (int u = 0; u < 8; ++u) {
      int idx = u * 256 + t;
      int s = idx >> 5, wb = idx & 31;
      coefc[s][wb] = bf2f(x[((size_t)(n * SEQ) + c * 64 + s) * DIMV + hb * 32 + wb]);
    }
    __syncthreads();
    #pragma unroll
    for (int u = 0; u < 8; ++u) {
      int idx = u * 256 + t;
      int wb = idx >> 6, iq = idx & 63;
      int i = iq >> 3, qq = iq & 7;
      float a = 0.f;
      #pragma unroll
      for (int p = 0; p < 8; ++p) a += DCT8c[i][p] * coefc[p * 8 + qq][wb];
      tmpA[i][wb * 8 + qq] = a;
    }
    __syncthreads();
    #pragma unroll
    for (int u = 0; u < 8; ++u) {
      int idx = u * 256 + t;
      int i = idx >> 8, xx = idx & 255;
      int wb = xx >> 3, j = xx & 7;
      float a = 0.f;
      #pragma unroll
      for (int qq = 0; qq < 8; ++qq) a += tmpA[i][wb * 8 + qq] * DCT8c[j][qq];
      rec[c][i][xx] = a;
    }
  }
  __syncthreads();
  #pragma unroll
  for (int u = 0; u < 8; ++u) {
    int idx = u * 256 + t;
    int i = idx >> 8, xx = idx & 255;
    float y = rec[0][i][xx], uu = rec[1][i][xx], v = rec[2][i][xx];
    size_t pix = ((size_t)(n * 3) * 256 + hb * 8 + i) * 256 + xx;
    out[pix]          = y + 1.13983f * v;
    out[pix + 65536]  = y - 0.39465f * uu - 0.5806f * v;
    out[pix + 131072] = y + 2.03211f * uu;
  }
}

// ---------------- weight transpose+convert: w[K][N] fp32 -> wt[N][K] bf16 ---
__global__ __launch_bounds__(256) void wconv_k(const float* __restrict__ w,
                                               unsigned short* __restrict__ wt,
                                               int K, int N) {
  size_t off = (size_t)blockIdx.z * K * N;
  w += off; wt += off;
  __shared__ float s[32][33];
  int t = threadIdx.x;
  int n0 = blockIdx.x << 5, k0 = blockIdx.y << 5;
  int r = t >> 3, c4 = (t & 7) << 2;
  float4 v = *(const float4*)(w + (size_t)(k0 + r) * N + n0 + c4);
  s[r][c4] = v.x; s[r][c4 + 1] = v.y; s[r][c4 + 2] = v.z; s[r][c4 + 3] = v.w;
  __syncthreads();
  ushort4 o;
  o.x = f2bf(s[c4 + 0][r]); o.y = f2bf(s[c4 + 1][r]);
  o.z = f2bf(s[c4 + 2][r]); o.w = f2bf(s[c4 + 3][r]);
  *(ushort4*)(wt + (size_t)(n0 + r) * K + k0 + c4) = o;
}

// ---------------- layernorm over last dim (1024): bf16 in -> bf16 out -------
__global__ __launch_bounds__(256) void ln_k(const unsigned short* __restrict__ x,
                                            const float* __restrict__ g,
                                            const float* __restrict__ b,
                                            unsigned short* __restrict__ out) {
  int row = blockIdx.x, t = threadIdx.x;
  ushort4 raw = ((const ushort4*)(x + (size_t)row * DIMV))[t];
  float v0 = bf2f(raw.x), v1 = bf2f(raw.y), v2 = bf2f(raw.z), v3 = bf2f(raw.w);
  float s  = v0 + v1 + v2 + v3;
  float s2 = v0 * v0 + v1 * v1 + v2 * v2 + v3 * v3;
  #pragma unroll
  for (int off = 32; off > 0; off >>= 1) {
    s  += __shfl_down(s,  off, 64);
    s2 += __shfl_down(s2, off, 64);
  }
  __shared__ float red[8];
  int w = t >> 6;
  if ((t & 63) == 0) { red[w] = s; red[4 + w] = s2; }
  __syncthreads();
  s  = red[0] + red[1] + red[2] + red[3];
  s2 = red[4] + red[5] + red[6] + red[7];
  float mu  = s * (1.f / 1024.f);
  float var = fmaxf(s2 * (1.f / 1024.f) - mu * mu, 0.f);
  float rs  = rsqrtf(var + 1e-5f);
  float4 gv = ((const float4*)g)[t];
  float4 bv = ((const float4*)b)[t];
  ushort4 ov;
  ov.x = f2bf((v0 - mu) * rs * gv.x + bv.x);
  ov.y = f2bf((v1 - mu) * rs * gv.y + bv.y);
  ov.z = f2bf((v2 - mu) * rs * gv.z + bv.z);
  ov.w = f2bf((v3 - mu) * rs * gv.w + bv.w);
  ((ushort4*)(out + (size_t)row * DIMV))[t] = ov;
}

// ---------------- bf16 MFMA GEMM: 128x64 tile, 4 waves, BK=64 (round 8) -----
// C[M,N] = A[M,K] @ Bt[N,K]^T. Wave w: quadrant (wm=(w>>1)*64, wn=(w&1)*32).
// Staging: gload16 covers 8 rows x 128 B -> 8 FULL cache lines/instr.
// Swizzle: physical 16B chunk p of row r holds logical chunk p^(r&7);
// lane loads global chunk (lane&7)^(lane>>3) (involution, rule #21).
// Pipeline: STAGE(0),STAGE(1); per it: vmcnt(6) -> s_barrier -> compute(it)
//           -> s_barrier -> STAGE(it+2). 6 loads/wave stay in flight.
// LDS: A[db] = db*16KB (128 rows x 128B); B[db] = 32KB + db*8KB (64 rows).
// EPI: 0 = plain->bf16, 1 = +bias+bf16 residual->bf16, 2 = +bias+GELU->bf16
template <int EPI>
__global__ __launch_bounds__(256) void mm_k(const unsigned short* __restrict__ A,
                                            const unsigned short* __restrict__ Bt,
                                            const float* __restrict__ bias,
                                            const unsigned short* res,
                                            unsigned short* Cout,
                                            int M, int N, int K) {
  __shared__ __align__(16) unsigned short smem[24576];   // 48 KB

  int t = threadIdx.x;
  int lane = t & 63, w = t >> 6;          // 4 waves
  // bijective XCD swizzle (all grids here are divisible by 8)
  int gx = gridDim.x;
  int nwg = gx * gridDim.y;
  int bid = blockIdx.y * gx + blockIdx.x;
  bid = (bid & 7) * (nwg >> 3) + (bid >> 3);
  int m0 = (bid / gx) << 7, n0 = (bid % gx) << 6;
  int wm = (w >> 1) << 6, wn = (w & 1) << 5;

  // staging: lane -> row offset r_in = lane>>3, physical chunk p = lane&7,
  // loads logical chunk p^r_in (8 elems) of its row.
  int r_in = lane >> 3, p = lane & 7;
  int sw = (p ^ r_in) << 3;
  const unsigned short* Ag = A + (size_t)(m0 + w * 32 + r_in) * K + sw;
  const unsigned short* Bg = Bt + (size_t)(n0 + w * 16 + r_in) * K + sw;
  char* smb = (char*)smem;
  size_t K8 = (size_t)K * 8;

  f32x4 acc[4][2] = {};

  int m15 = lane & 15, c4 = lane >> 4, s7 = lane & 7;
  int nt = K >> 6;

  #define STAGE(it_, db_) {                                                    \
    size_t k0_ = (size_t)(it_) << 6;                                           \
    gload16(Ag + k0_,          smb + (db_) * 16384 + ((w * 32 +  0) << 7));    \
    gload16(Ag + k0_ + K8,     smb + (db_) * 16384 + ((w * 32 +  8) << 7));    \
    gload16(Ag + k0_ + 2 * K8, smb + (db_) * 16384 + ((w * 32 + 16) << 7));    \
    gload16(Ag + k0_ + 3 * K8, smb + (db_) * 16384 + ((w * 32 + 24) << 7));    \
    gload16(Bg + k0_,          smb + 32768 + (db_) * 8192 + ((w * 16 + 0) << 7)); \
    gload16(Bg + k0_ + K8,     smb + 32768 + (db_) * 8192 + ((w * 16 + 8) << 7)); }

  STAGE(0, 0);
  STAGE(1, 1);

  for (int it = 0; it < nt; ++it) {
    int db = it & 1;
    if (it + 1 < nt) asm volatile("s_waitcnt vmcnt(6)" ::: "memory");
    else             asm volatile("s_waitcnt vmcnt(0)" ::: "memory");
    __builtin_amdgcn_s_barrier();
    const char* Ab = smb + db * 16384;
    const char* Bb = smb + 32768 + db * 8192;
    short8v a[2][4], b[2][2];
    #pragma unroll
    for (int kc = 0; kc < 2; ++kc) {
      int ch = ((kc << 2) + c4);
      #pragma unroll
      for (int mi = 0; mi < 4; ++mi)
        a[kc][mi] = *(const short8v*)(Ab + ((wm + mi * 16 + m15) << 7) + ((ch ^ s7) << 4));
      #pragma unroll
      for (int ni = 0; ni < 2; ++ni)
        b[kc][ni] = *(const short8v*)(Bb + ((wn + ni * 16 + m15) << 7) + ((ch ^ s7) << 4));
    }
    #pragma unroll
    for (int kc = 0; kc < 2; ++kc)
      #pragma unroll
      for (int mi = 0; mi < 4; ++mi)
        #pragma unroll
        for (int ni = 0; ni < 2; ++ni)
          acc[mi][ni] = __builtin_amdgcn_mfma_f32_16x16x32_bf16(a[kc][mi], b[kc][ni], acc[mi][ni], 0, 0, 0);
    __builtin_amdgcn_s_barrier();
    if (it + 2 < nt) STAGE(it + 2, db);
  }
  #undef STAGE

  // epilogue: C/D frag layout col = lane&15, row = (lane>>4)*4 + r  [m89/m91]
  int cn = lane & 15;
  int rbq = (lane >> 4) << 2;
  #pragma unroll
  for (int mi = 0; mi < 4; ++mi) {
    #pragma unroll
    for (int ni = 0; ni < 2; ++ni) {
      int col = n0 + wn + ni * 16 + cn;
      #pragma unroll
      for (int r = 0; r < 4; ++r) {
        int row = m0 + wm + mi * 16 + rbq + r;
        float v = acc[mi][ni][r];
        if (EPI >= 1) v += bias[col];
        if (EPI == 1) {
          v += bf2f(res[(size_t)row * N + col]);
          Cout[(size_t)row * N + col] = f2bf(v);
        } else if (EPI == 2) {
          v = 0.5f * v * (1.f + erff(v * 0.70710678f));
          Cout[(size_t)row * N + col] = f2bf(v);
        } else {
          Cout[(size_t)row * N + col] = f2bf(v);
        }
      }
    }
  }
}

// ---------------- MFMA attention (round 3, unchanged) -----------------------
__global__ __launch_bounds__(256) void attn_k(const unsigned short* __restrict__ qkv,
                                              unsigned short* __restrict__ o) {
  int qt = blockIdx.x, h = blockIdx.y, n = blockIdx.z;
  int t = threadIdx.x, lane = t & 63, w = t >> 6;
  __shared__ __align__(16) unsigned short Ks[192 * 64];
  __shared__ __align__(16) unsigned short Vt[64 * 192];
  __shared__ __align__(16) unsigned short Ps[4][16 * 192];
  const unsigned short* base = qkv + (size_t)n * SEQ * 1536;

  #pragma unroll
  for (int i = 0; i < 6; ++i) {
    int idx = i * 256 + t;
    int row = idx >> 3, c8 = (idx & 7) << 3;
    short8v kv = *(const short8v*)(base + (size_t)row * 1536 + 512 + h * 64 + c8);
    int kb = (row * 128 + c8 * 2) ^ ((row & 7) << 4);
    *(short8v*)((char*)Ks + kb) = kv;
  }
  #pragma unroll
  for (int i = 0; i < 6; ++i) {
    int idx = i * 256 + t;
    int j = (idx & 63) + ((idx >> 9) << 6);
    int d0 = ((idx >> 6) & 7) << 3;
    short8v vv = *(const short8v*)(base + (size_t)j * 1536 + 1024 + h * 64 + d0);
    #pragma unroll
    for (int e = 0; e < 8; ++e) {
      int d = d0 + e;
      int vb = (d * 384 + j * 2) ^ ((d & 7) << 4);
      *(unsigned short*)((char*)Vt + vb) = (unsigned short)vv[e];
    }
  }
  int q0 = qt * 64 + w * 16;
  const unsigned short* qp = base + (size_t)(q0 + (lane & 15)) * 1536 + h * 64 + ((lane >> 4) << 3);
  short8v aq0 = *(const short8v*)(qp);
  short8v aq1 = *(const short8v*)(qp + 32);
  __syncthreads();

  f32x4 sa[12];
  #pragma unroll
  for (int ni = 0; ni < 12; ++ni) sa[ni] = (f32x4){0.f, 0.f, 0.f, 0.f};
  #pragma unroll
  for (int ks = 0; ks < 2; ++ks) {
    int kk = (ks << 5) + ((lane >> 4) << 3);
    short8v aq = ks ? aq1 : aq0;
    #pragma unroll
    for (int ni = 0; ni < 12; ++ni) {
      int krow = ni * 16 + (lane & 15);
      int kb = (krow * 128 + kk * 2) ^ ((krow & 7) << 4);
      short8v bk = *(const short8v*)((char*)Ks + kb);
      sa[ni] = __builtin_amdgcn_mfma_f32_16x16x32_bf16(aq, bk, sa[ni], 0, 0, 0);
    }
  }

  unsigned short* Pw = Ps[w];
  float l4[4];
  #pragma unroll
  for (int r = 0; r < 4; ++r) {
    float mx = sa[0][r];
    #pragma unroll
    for (int ni = 1; ni < 12; ++ni) mx = fmaxf(mx, sa[ni][r]);
    mx = fmaxf(mx, __shfl_xor(mx, 1, 64));
    mx = fmaxf(mx, __shfl_xor(mx, 2, 64));
    mx = fmaxf(mx, __shfl_xor(mx, 4, 64));
    mx = fmaxf(mx, __shfl_xor(mx, 8, 64));
    int prow = ((lane >> 4) << 2) + r;
    float sum = 0.f;
    #pragma unroll
    for (int ni = 0; ni < 12; ++ni) {
      float p = __expf((sa[ni][r] - mx) * 0.125f);
      sum += p;
      int col = ni * 16 + (lane & 15);
      int pb = (prow * 384 + col * 2) ^ ((prow & 7) << 4);
      *(unsigned short*)((char*)Pw + pb) = f2bf(p);
    }
    sum += __shfl_xor(sum, 1, 64);
    sum += __shfl_xor(sum, 2, 64);
    sum += __shfl_xor(sum, 4, 64);
    sum += __shfl_xor(sum, 8, 64);
    l4[r] = sum;
  }

  f32x4 oa[4];
  #pragma unroll
  for (int ni = 0; ni < 4; ++ni) oa[ni] = (f32x4){0.f, 0.f, 0.f, 0.f};
  #pragma unroll
  for (int ks = 0; ks < 6; ++ks) {
    int kk = (ks << 5) + ((lane >> 4) << 3);
    int m = lane & 15;
    int pb = (m * 384 + kk * 2) ^ ((m & 7) << 4);
    short8v pa = *(const short8v*)((char*)Pw + pb);
    #pragma unroll
    for (int ni = 0; ni < 4; ++ni) {
      int vrow = ni * 16 + (lane & 15);
      int vb = (vrow * 384 + kk * 2) ^ ((vrow & 7) << 4);
      short8v vbf = *(const short8v*)((char*)Vt + vb);
      oa[ni] = __builtin_amdgcn_mfma_f32_16x16x32_bf16(pa, vbf, oa[ni], 0, 0, 0);
    }
  }

  int rbq = (lane >> 4) << 2;
  #pragma unroll
  for (int r = 0; r < 4; ++r) {
    float inv = 1.f / l4[r];
    unsigned short* dst = o + (size_t)(n * SEQ + q0 + rbq + r) * 512 + h * 64 + (lane & 15);
    #pragma unroll
    for (int ni = 0; ni < 4; ++ni)
      dst[ni * 16] = f2bf(oa[ni][r] * inv);
  }
}

// ---------------------------------------------------------------------------
extern "C" void kernel_launch(void* const* d_in, const int* in_sizes, int n_in,
                              void* d_out, int out_size, void* d_ws, size_t ws_size,
                              hipStream_t stream) {
  const float* img   = (const float*)d_in[0];
  const float* ln1_g = (const float*)d_in[1];
  const float* ln1_b = (const float*)d_in[2];
  const float* wqkv  = (const float*)d_in[3];
  const float* wo    = (const float*)d_in[4];
  const float* bo    = (const float*)d_in[5];
  const float* ln2_g = (const float*)d_in[6];
  const float* ln2_b = (const float*)d_in[7];
  const float* w1    = (const float*)d_in[8];
  const float* b1    = (const float*)d_in[9];
  const float* w2    = (const float*)d_in[10];
  const float* b2    = (const float*)d_in[11];
  float* out = (float*)d_out;

  char* ws = (char*)d_ws;
  unsigned short* x   = (unsigned short*)ws;                //  6,291,456 (bf16)
  unsigned short* xn  = (unsigned short*)(ws + 6291456);    //  6,291,456
  unsigned short* big = (unsigned short*)(ws + 12582912);   // 12,582,912
  unsigned short* ob  = (unsigned short*)(ws + 25165824);   //  3,145,728
  unsigned short* wtb = (unsigned short*)(ws + 28311552);   // weight area

  // all-layer weight area needs 75,497,472 B -> total 103,809,024
  bool big_ws = (ws_size >= 103809024ull);
  size_t per_qkv = (size_t)1024 * 1536, per_o = (size_t)512 * 1024;
  size_t per_1   = (size_t)1024 * 2048, per_2 = (size_t)2048 * 1024;
  unsigned short *wt_qkv, *wt_o, *wt_1, *wt_2;
  if (big_ws) {
    wt_qkv = wtb;
    wt_o   = wt_qkv + 6 * per_qkv;
    wt_1   = wt_o   + 6 * per_o;
    wt_2   = wt_1   + 6 * per_1;
    wconv_k<<<dim3(1536 / 32, 1024 / 32, 6), 256, 0, stream>>>(wqkv, wt_qkv, 1024, 1536);
    wconv_k<<<dim3(1024 / 32,  512 / 32, 6), 256, 0, stream>>>(wo,   wt_o,    512, 1024);
    wconv_k<<<dim3(2048 / 32, 1024 / 32, 6), 256, 0, stream>>>(w1,   wt_1,   1024, 2048);
    wconv_k<<<dim3(1024 / 32, 2048 / 32, 6), 256, 0, stream>>>(w2,   wt_2,   2048, 1024);
  } else {
    wt_qkv = wtb;
    wt_o   = wt_qkv + per_qkv;
    wt_1   = wt_o + per_o;
    wt_2   = wt_1 + per_1;
  }

  preproc_k<<<dim3(32, 16), 256, 0, stream>>>(img, x);

  for (int l = 0; l < 6; ++l) {
    unsigned short *wq_l, *wo_l, *w1_l, *w2_l;
    if (big_ws) {
      wq_l = wt_qkv + l * per_qkv; wo_l = wt_o + l * per_o;
      w1_l = wt_1 + l * per_1;     w2_l = wt_2 + l * per_2;
    } else {
      wconv_k<<<dim3(1536 / 32, 1024 / 32), 256, 0, stream>>>(wqkv + l * per_qkv, wt_qkv, 1024, 1536);
      wconv_k<<<dim3(1024 / 32,  512 / 32), 256, 0, stream>>>(wo   + l * per_o,   wt_o,    512, 1024);
      wconv_k<<<dim3(2048 / 32, 1024 / 32), 256, 0, stream>>>(w1   + l * per_1,   wt_1,   1024, 2048);
      wconv_k<<<dim3(1024 / 32, 2048 / 32), 256, 0, stream>>>(w2   + l * per_2,   wt_2,   2048, 1024);
      wq_l = wt_qkv; wo_l = wt_o; w1_l = wt_1; w2_l = wt_2;
    }

    ln_k<<<MROWS, 256, 0, stream>>>(x, ln1_g + l * 1024, ln1_b + l * 1024, xn);
    mm_k<0><<<dim3(1536 / 64, 24), 256, 0, stream>>>(xn, wq_l, nullptr, nullptr, big, MROWS, 1536, 1024);
    attn_k<<<dim3(3, 8, 16), 256, 0, stream>>>(big, ob);
    mm_k<1><<<dim3(1024 / 64, 24), 256, 0, stream>>>(ob, wo_l, bo + l * 1024, x, x, MROWS, 1024, 512);
    ln_k<<<MROWS, 256, 0, stream>>>(x, ln2_g + l * 1024, ln2_b + l * 1024, xn);
    mm_k<2><<<dim3(2048 / 64, 24), 256, 0, stream>>>(xn, w1_l, b1 + l * 2048, nullptr, big, MROWS, 2048, 1024);
    mm_k<1><<<dim3(1024 / 64, 24), 256, 0, stream>>>(big, w2_l, b2 + l * 1024, x, x, MROWS, 1024, 2048);
  }

  postproc_k<<<dim3(32, 16), 256, 0, stream>>>(x, out);
}